// Round 15
// baseline (25681.418 us; speedup 1.0000x reference)
//
#include <hip/hip_runtime.h>
#include <math.h>

typedef __attribute__((ext_vector_type(8))) short short8;
typedef __attribute__((ext_vector_type(4))) float f32x4;
typedef unsigned short ushort_t;

constexpr int NV = 50000;    // V
constexpr int NL = 100000;   // 2V literal rows
constexpr int NC = 200000;   // clauses
constexpr int NE = 300000;   // edges per polarity
constexpr int NROUNDS = 26;

// NOTE (r8 post-mortem): epilogue math must be relative-error-only. tanh via
// 1 - 2/(e^2x+1) has additive ~ulp(1)=6e-8 cancellation at small x -> breaks
// the 8.8e-8 threshold over 26 recurrent rounds. Keep libm tanhf.
__device__ __forceinline__ float sigf(float x) { return 1.0f / (1.0f + __expf(-x)); }

// f32 -> bf16 hi/lo split (truncation; h+l rel err ~2^-17)
__device__ __forceinline__ void split1(float x, ushort_t* h, ushort_t* l) {
    unsigned u = __float_as_uint(x);
    *h = (ushort_t)(u >> 16);
    float lf = x - __uint_as_float(u & 0xffff0000u);
    *l = (ushort_t)(__float_as_uint(lf) >> 16);
}
__device__ __forceinline__ float recf(ushort_t h, ushort_t l) {
    return __uint_as_float((unsigned)h << 16) + __uint_as_float((unsigned)l << 16);
}

// weight split with RTN on both halves (one-time prep)
__device__ __forceinline__ void splitw(float x, ushort_t* h, ushort_t* l) {
    unsigned u = __float_as_uint(x);
    unsigned hr = (u + 0x7fffu + ((u >> 16) & 1u)) & 0xffff0000u;
    float lf = x - __uint_as_float(hr);
    unsigned ul = __float_as_uint(lf);
    *h = (ushort_t)(hr >> 16);
    *l = (ushort_t)((ul + 0x7fffu + ((ul >> 16) & 1u)) >> 16);
}

// ===== activation layout: row record = 256 ushorts: [0:128]=hi[k], [128:256]=lo[k] =====

__global__ __launch_bounds__(256) void split_rows_k(
    const float* __restrict__ src, ushort_t* __restrict__ dst, int total)
{
    for (int i = blockIdx.x * 256 + threadIdx.x; i < total; i += gridDim.x * 256) {
        int row = i >> 7, c = i & 127;
        ushort_t h, l;
        split1(src[i], &h, &l);
        dst[(size_t)row * 256 + c] = h;
        dst[(size_t)row * 256 + 128 + c] = l;
    }
}

__global__ __launch_bounds__(256) void convert_out_k(
    const ushort_t* __restrict__ src, float* __restrict__ dst, int total)
{
    for (int i = blockIdx.x * 256 + threadIdx.x; i < total; i += gridDim.x * 256) {
        int row = i >> 7, c = i & 127;
        dst[i] = recf(src[(size_t)row * 256 + c], src[(size_t)row * 256 + 128 + c]);
    }
}

// ======== weight prep: fragment-major packed layouts ========
// frag id: (((kt*NT + tile)*64 + lane)*8 + j); elem = W^T[n = tile*16 + (lane&15)][k = kt*32 + (lane>>4)*8 + j]

__global__ __launch_bounds__(256) void pack_mlp_frag(
    const float* __restrict__ W, ushort_t* __restrict__ Wh, ushort_t* __restrict__ Wl)
{
    int fid = blockIdx.x * 256 + threadIdx.x;   // 3*4*8*64 = 6144
    if (fid >= 6144) return;
    int lane = fid & 63;
    int tile = (fid >> 6) & 7;
    int kt = (fid >> 9) & 3;
    int layer = fid >> 11;
    int l15 = lane & 15, lg = lane >> 4;
    int n = tile * 16 + l15;
#pragma unroll
    for (int j = 0; j < 8; j++) {
        int k = kt * 32 + lg * 8 + j;
        ushort_t h, l;
        splitw(W[layer * 16384 + k * 128 + n], &h, &l);
        Wh[(size_t)fid * 8 + j] = h;
        Wl[(size_t)fid * 8 + j] = l;
    }
}

__global__ __launch_bounds__(256) void pack_lstm_frag(
    const float* __restrict__ Wih, const float* __restrict__ Whh, int kih, int nstep,
    ushort_t* __restrict__ Wh, ushort_t* __restrict__ Wl)
{
    int fid = blockIdx.x * 256 + threadIdx.x;   // nstep*32*64
    if (fid >= nstep * 2048) return;
    int lane = fid & 63;
    int tile = (fid >> 6) & 31;
    int kt = fid >> 11;
    int l15 = lane & 15, lg = lane >> 4;
    int n = tile * 16 + l15;
#pragma unroll
    for (int j = 0; j < 8; j++) {
        int k = kt * 32 + lg * 8 + j;
        float v = (k < kih) ? Wih[n * kih + k] : Whh[(n << 7) + (k - kih)];
        ushort_t h, l;
        splitw(v, &h, &l);
        Wh[(size_t)fid * 8 + j] = h;
        Wl[(size_t)fid * 8 + j] = l;
    }
}

// ================= CSR build (once per call) =================
__global__ __launch_bounds__(256) void csr_hist_k(
    const int* __restrict__ ps, const int* __restrict__ pd,
    const int* __restrict__ ns, const int* __restrict__ nd,
    int* __restrict__ cnt_c, int* __restrict__ cnt_l)
{
    int e = blockIdx.x * 256 + threadIdx.x;
    if (e >= NE) return;
    atomicAdd(&cnt_c[pd[e]], 1);
    atomicAdd(&cnt_c[nd[e]], 1);
    atomicAdd(&cnt_l[ps[e]], 1);
    atomicAdd(&cnt_l[NV + ns[e]], 1);
}

__global__ __launch_bounds__(256) void scan_p1(
    const int* __restrict__ cnt, int* __restrict__ partials, int n)
{
    __shared__ int sdata[256];
    int t = threadIdx.x, b = blockIdx.x;
    int base = b * 1024 + t * 4;
    int s = 0;
#pragma unroll
    for (int j = 0; j < 4; j++) { int i = base + j; if (i < n) s += cnt[i]; }
    sdata[t] = s; __syncthreads();
    for (int st = 128; st > 0; st >>= 1) {
        if (t < st) sdata[t] += sdata[t + st];
        __syncthreads();
    }
    if (t == 0) partials[b] = sdata[0];
}

__global__ __launch_bounds__(256) void scan_p2(int* __restrict__ partials, int nb, int* __restrict__ rowptr_end)
{
    __shared__ int sdata[256];
    int t = threadIdx.x;
    int v = (t < nb) ? partials[t] : 0;
    int x = v;
    sdata[t] = x; __syncthreads();
    for (int st = 1; st < 256; st <<= 1) {
        int y = (t >= st) ? sdata[t - st] : 0;
        __syncthreads();
        x += y; sdata[t] = x;
        __syncthreads();
    }
    if (t < nb) partials[t] = x - v;
    if (t == 255) *rowptr_end = sdata[255];
}

__global__ __launch_bounds__(256) void scan_p3(
    const int* __restrict__ cnt, const int* __restrict__ partials,
    int* __restrict__ rowptr, int* __restrict__ cursor, int n)
{
    __shared__ int sdata[256];
    int t = threadIdx.x, b = blockIdx.x;
    int base = b * 1024 + t * 4;
    int v[4]; int s = 0;
#pragma unroll
    for (int j = 0; j < 4; j++) { int i = base + j; v[j] = (i < n) ? cnt[i] : 0; s += v[j]; }
    int x = s;
    sdata[t] = x; __syncthreads();
    for (int st = 1; st < 256; st <<= 1) {
        int y = (t >= st) ? sdata[t - st] : 0;
        __syncthreads();
        x += y; sdata[t] = x;
        __syncthreads();
    }
    int off = partials[b] + x - s;
#pragma unroll
    for (int j = 0; j < 4; j++) {
        int i = base + j;
        if (i < n) { rowptr[i] = off; cursor[i] = off; off += v[j]; }
    }
}

__global__ __launch_bounds__(256) void csr_fill_k(
    const int* __restrict__ ps, const int* __restrict__ pd,
    const int* __restrict__ ns, const int* __restrict__ nd,
    int* __restrict__ cur_c, int* __restrict__ eidx_c,
    int* __restrict__ cur_l, int* __restrict__ eidx_l)
{
    int e = blockIdx.x * 256 + threadIdx.x;
    if (e >= NE) return;
    int p;
    p = atomicAdd(&cur_c[pd[e]], 1); eidx_c[p] = ps[e];
    p = atomicAdd(&cur_c[nd[e]], 1); eidx_c[p] = NV + ns[e];
    p = atomicAdd(&cur_l[ps[e]], 1); eidx_l[p] = pd[e];
    p = atomicAdd(&cur_l[NV + ns[e]], 1); eidx_l[p] = nd[e];
}

// ---- gather-sum over split rows: out[row] = sum msg[eidx[j]] ; one wave per row ----
__global__ __launch_bounds__(256) void gather_sum_k(
    const ushort_t* __restrict__ msg, const int* __restrict__ rowptr,
    const int* __restrict__ eidx, ushort_t* __restrict__ out, int nrows)
{
    int row = (blockIdx.x * 256 + threadIdx.x) >> 6;
    if (row >= nrows) return;
    int lane = threadIdx.x & 63;
    int beg = rowptr[row], end = rowptr[row + 1];
    float a0 = 0.f, a1 = 0.f;
    for (int j = beg; j < end; j++) {
        int src = eidx[j];
        const ushort_t* p = msg + (size_t)src * 256 + lane * 2;
        unsigned hp = *reinterpret_cast<const unsigned*>(p);
        unsigned lp = *reinterpret_cast<const unsigned*>(p + 128);
        a0 += __uint_as_float(hp << 16) + __uint_as_float(lp << 16);
        a1 += __uint_as_float(hp & 0xffff0000u) + __uint_as_float(lp & 0xffff0000u);
    }
    ushort_t h0, l0, h1, l1;
    split1(a0, &h0, &l0);
    split1(a1, &h1, &l1);
    ushort_t* op = out + (size_t)row * 256 + lane * 2;
    *reinterpret_cast<unsigned*>(op) = (unsigned)h0 | ((unsigned)h1 << 16);
    *reinterpret_cast<unsigned*>(op + 128) = (unsigned)l0 | ((unsigned)l1 << 16);
}

// ---------------- fused 3-layer MLP: split-plane input/output, LDS activation bounce ----------------
__global__ __launch_bounds__(256, 4) void mlp3_v5(
    const ushort_t* __restrict__ x, const ushort_t* __restrict__ Wh,
    const ushort_t* __restrict__ Wl, const float* __restrict__ bias,
    ushort_t* __restrict__ y, int M)
{
    __shared__ ushort_t Xh[64][136];
    __shared__ ushort_t Xl[64][136];
    const int t = threadIdx.x;
    const int rb = blockIdx.x * 64;
    const int lane = t & 63, w = t >> 6, wr = w >> 1, wc = w & 1;
    const int l15 = lane & 15, lg = lane >> 4;

#pragma unroll
    for (int j = 0; j < 8; j++) {
        int idx = t + 256 * j;             // [0,2048)
        int plane = idx >> 10, rem = idx & 1023;
        int r = rem >> 4, c8 = (rem & 15) * 8;
        int gr = rb + r; if (gr >= M) gr = M - 1;
        uint4 v = *reinterpret_cast<const uint4*>(x + (size_t)gr * 256 + plane * 128 + c8);
        ushort_t* dst = plane ? &Xl[r][c8] : &Xh[r][c8];
        *reinterpret_cast<uint4*>(dst) = v;
    }
    __syncthreads();

    for (int layer = 0; layer < 3; layer++) {
        f32x4 acc[2][4];
#pragma unroll
        for (int m = 0; m < 2; m++)
#pragma unroll
            for (int nf = 0; nf < 4; nf++) acc[m][nf] = f32x4{0.f, 0.f, 0.f, 0.f};

        short8 bh[4], bl[4], bhn[4], bln[4];
#pragma unroll
        for (int nf = 0; nf < 4; nf++) {
            int tile = wc * 4 + nf;
            size_t off = ((size_t)((layer * 4 + 0) * 8 + tile) * 64 + lane) * 8;
            bh[nf] = *reinterpret_cast<const short8*>(Wh + off);
            bl[nf] = *reinterpret_cast<const short8*>(Wl + off);
        }

#pragma unroll
        for (int kt = 0; kt < 4; kt++) {
            short8 ah[2], al[2];
#pragma unroll
            for (int m = 0; m < 2; m++) {
                int row = wr * 32 + m * 16 + l15;
                ah[m] = *reinterpret_cast<const short8*>(&Xh[row][kt * 32 + lg * 8]);
                al[m] = *reinterpret_cast<const short8*>(&Xl[row][kt * 32 + lg * 8]);
            }
            if (kt < 3) {
#pragma unroll
                for (int nf = 0; nf < 4; nf++) {
                    int tile = wc * 4 + nf;
                    size_t off = ((size_t)((layer * 4 + kt + 1) * 8 + tile) * 64 + lane) * 8;
                    bhn[nf] = *reinterpret_cast<const short8*>(Wh + off);
                    bln[nf] = *reinterpret_cast<const short8*>(Wl + off);
                }
            }
#pragma unroll
            for (int nf = 0; nf < 4; nf++)
#pragma unroll
                for (int m = 0; m < 2; m++)
                    acc[m][nf] = __builtin_amdgcn_mfma_f32_16x16x32_bf16(ah[m], bh[nf], acc[m][nf], 0, 0, 0);
#pragma unroll
            for (int nf = 0; nf < 4; nf++)
#pragma unroll
                for (int m = 0; m < 2; m++)
                    acc[m][nf] = __builtin_amdgcn_mfma_f32_16x16x32_bf16(ah[m], bl[nf], acc[m][nf], 0, 0, 0);
#pragma unroll
            for (int nf = 0; nf < 4; nf++)
#pragma unroll
                for (int m = 0; m < 2; m++)
                    acc[m][nf] = __builtin_amdgcn_mfma_f32_16x16x32_bf16(al[m], bh[nf], acc[m][nf], 0, 0, 0);
            if (kt < 3) {
#pragma unroll
                for (int nf = 0; nf < 4; nf++) { bh[nf] = bhn[nf]; bl[nf] = bln[nf]; }
            }
        }

        float bv[4];
#pragma unroll
        for (int nf = 0; nf < 4; nf++) bv[nf] = bias[layer * 128 + wc * 64 + nf * 16 + l15];
        __syncthreads();   // all Xh/Xl reads done
        if (layer < 2) {
#pragma unroll
            for (int m = 0; m < 2; m++)
#pragma unroll
                for (int nf = 0; nf < 4; nf++)
#pragma unroll
                    for (int rr = 0; rr < 4; rr++) {
                        float v = fmaxf(acc[m][nf][rr] + bv[nf], 0.f);
                        ushort_t h, l;
                        split1(v, &h, &l);
                        int rw = wr * 32 + m * 16 + lg * 4 + rr;
                        int cl = wc * 64 + nf * 16 + l15;
                        Xh[rw][cl] = h;
                        Xl[rw][cl] = l;
                    }
            __syncthreads();
        } else {
#pragma unroll
            for (int m = 0; m < 2; m++)
#pragma unroll
                for (int rr = 0; rr < 4; rr++) {
                    int gr = rb + wr * 32 + m * 16 + lg * 4 + rr;
                    if (gr < M) {
#pragma unroll
                        for (int nf = 0; nf < 4; nf++) {
                            float v = acc[m][nf][rr] + bv[nf];
                            ushort_t h, l;
                            split1(v, &h, &l);
                            size_t p = (size_t)gr * 256 + wc * 64 + nf * 16 + l15;
                            y[p] = h;
                            y[p + 128] = l;
                        }
                    }
                }
        }
    }
}

// ---------------- LSTM v9: NO LDS, NO BARRIERS — free-running waves, TLP-saturated MFMA ----------------
// Hypothesis test (r14 post-mortem): per-kt __syncthreads + vmcnt(0) drain convoys all waves of a
// block onto the slowest HBM load; removing all intra-block sync lets co-resident waves' stalls
// decorrelate and the matrix pipe saturate via TLP.
// Same XCD-grouped (tile, slice) grid as v8: wg = r8 + 8*(4*q + s), xcd = wg%8.
// block 256 thr / 4 INDEPENDENT waves; wave = 32 rows x (4 gates x 16 slice-cols); acc[2][4].
// Per wave-kt: 4 A uint4 loads (same addresses the LDS staging used; wc-pair -> L2 hit),
// 8 batched B frag loads (L2, XCD-shared), 24 MFMAs. A prefetched 1 kt ahead in registers.
template <int NKT, bool FLIP>
__global__ __launch_bounds__(256, 4) void lstm_v9(
    const ushort_t* __restrict__ A0, const ushort_t* __restrict__ A1, const ushort_t* __restrict__ A2,
    const ushort_t* __restrict__ Bh_g, const ushort_t* __restrict__ Bl_g,
    const float* __restrict__ bih, const float* __restrict__ bhh,
    float* __restrict__ c_st, ushort_t* __restrict__ h_out, int M)
{
    const int wg = blockIdx.x;
    const int r8 = wg & 7, j = wg >> 3;
    const int s = j & 3;
    const int tile_id = r8 + 8 * (j >> 2);
    const int rb = tile_id * 64;
    if (rb >= M) return;                      // padding block

    const int t = threadIdx.x;
    const int lane = t & 63, w = t >> 6, wr = w >> 1, wc = w & 1;
    const int l15 = lane & 15, lg = lane >> 4;

    // per-wave row indices for its 2 m-tiles (16 rows each)
    int r0[2], rF[2];
#pragma unroll
    for (int m = 0; m < 2; m++) {
        int r = rb + (wr * 2 + m) * 16 + l15;
        if (r >= M) r = M - 1;
        r0[m] = r;
        rF[m] = FLIP ? ((r < NV) ? r + NV : r - NV) : r;
    }

    f32x4 acc[2][4];
#pragma unroll
    for (int m = 0; m < 2; m++)
#pragma unroll
        for (int g = 0; g < 4; g++) acc[m][g] = f32x4{0.f, 0.f, 0.f, 0.f};

    // preload kt=0 A frags (seg 0 = A0, never flipped)
    short8 ah[2], al[2];
#pragma unroll
    for (int m = 0; m < 2; m++) {
        const ushort_t* p = A0 + (size_t)r0[m] * 256 + lg * 8;
        ah[m] = *reinterpret_cast<const short8*>(p);
        al[m] = *reinterpret_cast<const short8*>(p + 128);
    }

#pragma unroll
    for (int kt = 0; kt < NKT; kt++) {
        // (1) batch-issue all 8 B-frag loads for this kt (L2-resident, XCD-shared)
        short8 bh[4], bl[4];
#pragma unroll
        for (int g = 0; g < 4; g++) {
            int gt = g * 8 + s * 2 + wc;
            size_t off = ((size_t)(kt * 32 + gt) * 64 + lane) * 8;
            bh[g] = *reinterpret_cast<const short8*>(Bh_g + off);
            bl[g] = *reinterpret_cast<const short8*>(Bl_g + off);
        }
        // (2) prefetch next-kt A frags into registers
        short8 ahn[2], aln[2];
        if (kt + 1 < NKT) {
            const int kn = kt + 1;
            const int seg = kn >> 2;
            const ushort_t* src = (seg == 0) ? A0 : ((seg == 1) ? A1 : A2);
            const bool useF = FLIP && (seg == 1);
            const int kco = (kn & 3) * 32;
#pragma unroll
            for (int m = 0; m < 2; m++) {
                const ushort_t* p = src + (size_t)(useF ? rF[m] : r0[m]) * 256 + kco + lg * 8;
                ahn[m] = *reinterpret_cast<const short8*>(p);
                aln[m] = *reinterpret_cast<const short8*>(p + 128);
            }
        }
        // (3) MFMA cluster (loads drain under the matrix work of co-resident waves)
#pragma unroll
        for (int g = 0; g < 4; g++) {
#pragma unroll
            for (int m = 0; m < 2; m++)
                acc[m][g] = __builtin_amdgcn_mfma_f32_16x16x32_bf16(ah[m], bh[g], acc[m][g], 0, 0, 0);
#pragma unroll
            for (int m = 0; m < 2; m++)
                acc[m][g] = __builtin_amdgcn_mfma_f32_16x16x32_bf16(ah[m], bl[g], acc[m][g], 0, 0, 0);
#pragma unroll
            for (int m = 0; m < 2; m++)
                acc[m][g] = __builtin_amdgcn_mfma_f32_16x16x32_bf16(al[m], bh[g], acc[m][g], 0, 0, 0);
        }
        if (kt + 1 < NKT) {
#pragma unroll
            for (int m = 0; m < 2; m++) { ah[m] = ahn[m]; al[m] = aln[m]; }
        }
    }

    // epilogue: bias + activations + state update; h written in split format
    const int colc = s * 32 + wc * 16 + l15;
    float bs4[4];
#pragma unroll
    for (int g = 0; g < 4; g++) bs4[g] = bih[g * 128 + colc] + bhh[g * 128 + colc];
#pragma unroll
    for (int m = 0; m < 2; m++)
#pragma unroll
        for (int rr = 0; rr < 4; rr++) {
            int gr = rb + (wr * 2 + m) * 16 + lg * 4 + rr;
            if (gr >= M) continue;
            float gi = acc[m][0][rr] + bs4[0];
            float gf = acc[m][1][rr] + bs4[1];
            float gg = acc[m][2][rr] + bs4[2];
            float go = acc[m][3][rr] + bs4[3];
            size_t pc = (size_t)gr * 128 + colc;
            float cold = c_st[pc];
            float cn = sigf(gf) * cold + sigf(gi) * tanhf(gg);
            float hn = sigf(go) * tanhf(cn);
            c_st[pc] = cn;
            ushort_t hh, hl;
            split1(hn, &hh, &hl);
            size_t ph = (size_t)gr * 256 + colc;
            h_out[ph] = hh;
            h_out[ph + 128] = hl;
        }
}

extern "C" void kernel_launch(void* const* d_in, const int* in_sizes, int n_in,
                              void* d_out, int out_size, void* d_ws, size_t ws_size,
                              hipStream_t stream)
{
    const float* l_pos   = (const float*)d_in[0];
    const float* l_neg   = (const float*)d_in[1];
    const float* c_emb   = (const float*)d_in[2];
    const float* l_mlp_W = (const float*)d_in[3];
    const float* l_mlp_b = (const float*)d_in[4];
    const float* c_mlp_W = (const float*)d_in[5];
    const float* c_mlp_b = (const float*)d_in[6];
    const float* l_Wih   = (const float*)d_in[7];
    const float* l_Whh   = (const float*)d_in[8];
    const float* l_bih   = (const float*)d_in[9];
    const float* l_bhh   = (const float*)d_in[10];
    const float* c_Wih   = (const float*)d_in[11];
    const float* c_Whh   = (const float*)d_in[12];
    const float* c_bih   = (const float*)d_in[13];
    const float* c_bhh   = (const float*)d_in[14];
    const int* pos_src   = (const int*)d_in[15];
    const int* pos_dst   = (const int*)d_in[16];
    const int* neg_src   = (const int*)d_in[17];
    const int* neg_dst   = (const int*)d_in[18];

    float* out = (float*)d_out;
    // d_out doubles as the h-state PONG buffers during rounds (dead by final convert):
    ushort_t* l_hQ = (ushort_t*)d_out;                       // NL rows x 512B
    ushort_t* c_hQ = (ushort_t*)(out + (size_t)NL * 128);    // NC rows x 512B

    float* wsp = (float*)d_ws;
    ushort_t* l_hP  = (ushort_t*)wsp; wsp += (size_t)NL * 128;   // literal h ping
    float*    l_c   = wsp;            wsp += (size_t)NL * 128;   // literal cell (f32)
    float*    c_c   = wsp;            wsp += (size_t)NC * 128;   // clause cell (f32)
    ushort_t* l_msg = (ushort_t*)wsp; wsp += (size_t)NL * 128;   // literal msg / c2l alias
    ushort_t* c_hP  = (ushort_t*)wsp; wsp += (size_t)NC * 128;   // clause h ping
    ushort_t* l2c   = (ushort_t*)wsp; wsp += (size_t)NC * 128;
    ushort_t* c2l = l_msg;  // gather #2 writes here after gather #1 consumed l_msg

    ushort_t* us = (ushort_t*)wsp;
    ushort_t* mlpLh = us; us += 3 * 128 * 128;
    ushort_t* mlpLl = us; us += 3 * 128 * 128;
    ushort_t* mlpCh = us; us += 3 * 128 * 128;
    ushort_t* mlpCl = us; us += 3 * 128 * 128;
    ushort_t* lstmLh = us; us += 512 * 384;
    ushort_t* lstmLl = us; us += 512 * 384;
    ushort_t* lstmCh = us; us += 512 * 256;
    ushort_t* lstmCl = us; us += 512 * 256;

    int* ip = (int*)us;
    int* cnt_c    = ip; ip += NC;
    int* rowptr_c = ip; ip += NC + 1;
    int* cur_c    = ip; ip += NC;
    int* eidx_c   = ip; ip += 2 * NE;
    int* cnt_l    = ip; ip += NL;
    int* rowptr_l = ip; ip += NL + 1;
    int* cur_l    = ip; ip += NL;
    int* eidx_l   = ip; ip += 2 * NE;
    int* part_c   = ip; ip += 256;
    int* part_l   = ip; ip += 256;

    // init states: split embeddings into ping buffers; zero cells
    split_rows_k<<<2048, 256, 0, stream>>>(l_pos, l_hP, NV * 128);
    split_rows_k<<<2048, 256, 0, stream>>>(l_neg, l_hP + (size_t)NV * 256, NV * 128);
    split_rows_k<<<2048, 256, 0, stream>>>(c_emb, c_hP, NC * 128);
    hipMemsetAsync(l_c, 0, (size_t)NL * 128 * 4, stream);
    hipMemsetAsync(c_c, 0, (size_t)NC * 128 * 4, stream);

    // pack weights (once per call)
    pack_mlp_frag<<<24, 256, 0, stream>>>(l_mlp_W, mlpLh, mlpLl);
    pack_mlp_frag<<<24, 256, 0, stream>>>(c_mlp_W, mlpCh, mlpCl);
    pack_lstm_frag<<<96, 256, 0, stream>>>(l_Wih, l_Whh, 256, 12, lstmLh, lstmLl);
    pack_lstm_frag<<<64, 256, 0, stream>>>(c_Wih, c_Whh, 128, 8, lstmCh, lstmCl);

    // ---- CSR build (once per call; graph static across rounds) ----
    hipMemsetAsync(cnt_c, 0, NC * sizeof(int), stream);
    hipMemsetAsync(cnt_l, 0, NL * sizeof(int), stream);
    constexpr int EB = (NE + 255) / 256;
    csr_hist_k<<<EB, 256, 0, stream>>>(pos_src, pos_dst, neg_src, neg_dst, cnt_c, cnt_l);
    constexpr int NBC = (NC + 1023) / 1024;
    constexpr int NBL = (NL + 1023) / 1024;
    scan_p1<<<NBC, 256, 0, stream>>>(cnt_c, part_c, NC);
    scan_p2<<<1, 256, 0, stream>>>(part_c, NBC, rowptr_c + NC);
    scan_p3<<<NBC, 256, 0, stream>>>(cnt_c, part_c, rowptr_c, cur_c, NC);
    scan_p1<<<NBL, 256, 0, stream>>>(cnt_l, part_l, NL);
    scan_p2<<<1, 256, 0, stream>>>(part_l, NBL, rowptr_l + NL);
    scan_p3<<<NBL, 256, 0, stream>>>(cnt_l, part_l, rowptr_l, cur_l, NL);
    csr_fill_k<<<EB, 256, 0, stream>>>(pos_src, pos_dst, neg_src, neg_dst,
                                       cur_c, eidx_c, cur_l, eidx_l);

    // swizzled LSTM grids: BM=64 tiles padded to x8 so (wg%8)-XCD mapping stays bijective
    constexpr int TL64 = (NL + 63) / 64, TLP64 = ((TL64 + 7) / 8) * 8;   // 1563 -> 1568
    constexpr int TC64 = (NC + 63) / 64, TCP64 = ((TC64 + 7) / 8) * 8;   // 3125 -> 3128

    ushort_t* l_cur = l_hP;
    ushort_t* l_nxt = l_hQ;
    ushort_t* c_cur = c_hP;
    ushort_t* c_oth = c_hQ;

    for (int r = 0; r < NROUNDS; r++) {
        // MLPs: l_cur -> l_msg ; c_cur -> c_oth (c_msg lives in the dead clause-h buffer)
        mlp3_v5<<<(NL + 63) / 64, 256, 0, stream>>>(l_cur, mlpLh, mlpLl, l_mlp_b, l_msg, NL);
        mlp3_v5<<<(NC + 63) / 64, 256, 0, stream>>>(c_cur, mlpCh, mlpCl, c_mlp_b, c_oth, NC);

        // gathers: l2c from l_msg ; c2l (aliases l_msg) from c_oth
        gather_sum_k<<<NC * 64 / 256, 256, 0, stream>>>(l_msg, rowptr_c, eidx_c, l2c, NC);
        gather_sum_k<<<NL * 64 / 256, 256, 0, stream>>>(c_oth, rowptr_l, eidx_l, c2l, NL);

        // literal LSTM: x = [c2l | flip(l_cur) | l_cur] -> l_nxt (l_c in place)
        lstm_v9<12, true><<<4 * TLP64, 256, 0, stream>>>(
            c2l, l_cur, l_cur, lstmLh, lstmLl, l_bih, l_bhh, l_c, l_nxt, NL);
        // clause LSTM: x = [l2c | c_cur] -> h into c_oth (c_msg already consumed; c_c in place)
        lstm_v9<8, false><<<4 * TCP64, 256, 0, stream>>>(
            l2c, c_cur, nullptr, lstmCh, lstmCl, c_bih, c_bhh, c_c, c_oth, NC);

        ushort_t* t2 = l_cur; l_cur = l_nxt; l_nxt = t2;
        t2 = c_cur; c_cur = c_oth; c_oth = t2;
    }
    // 26 even rounds: l_cur == l_hP (ws), c_cur == c_hP (ws). Pongs in d_out are dead.
    convert_out_k<<<2048, 256, 0, stream>>>(l_hP, out, NL * 128);
    convert_out_k<<<2048, 256, 0, stream>>>(c_hP, out + (size_t)NL * 128, NC * 128);
    (void)in_sizes; (void)n_in; (void)out_size; (void)ws_size;
}

// Round 16
// 20470.459 us; speedup vs baseline: 1.2546x; 1.2546x over previous
//
#include <hip/hip_runtime.h>
#include <math.h>

typedef __attribute__((ext_vector_type(8))) short short8;
typedef __attribute__((ext_vector_type(4))) float f32x4;
typedef unsigned short ushort_t;

constexpr int NV = 50000;    // V
constexpr int NL = 100000;   // 2V literal rows
constexpr int NC = 200000;   // clauses
constexpr int NE = 300000;   // edges per polarity
constexpr int NROUNDS = 26;

// NOTE (r8 post-mortem): epilogue math must be relative-error-only. tanh via
// 1 - 2/(e^2x+1) has additive ~ulp(1)=6e-8 cancellation at small x -> breaks
// the 8.8e-8 threshold over 26 recurrent rounds. Keep libm tanhf.
__device__ __forceinline__ float sigf(float x) { return 1.0f / (1.0f + __expf(-x)); }

// f32 -> bf16 hi/lo split (truncation; h+l rel err ~2^-17)
__device__ __forceinline__ void split1(float x, ushort_t* h, ushort_t* l) {
    unsigned u = __float_as_uint(x);
    *h = (ushort_t)(u >> 16);
    float lf = x - __uint_as_float(u & 0xffff0000u);
    *l = (ushort_t)(__float_as_uint(lf) >> 16);
}
__device__ __forceinline__ float recf(ushort_t h, ushort_t l) {
    return __uint_as_float((unsigned)h << 16) + __uint_as_float((unsigned)l << 16);
}

// weight split with RTN on both halves (one-time prep)
__device__ __forceinline__ void splitw(float x, ushort_t* h, ushort_t* l) {
    unsigned u = __float_as_uint(x);
    unsigned hr = (u + 0x7fffu + ((u >> 16) & 1u)) & 0xffff0000u;
    float lf = x - __uint_as_float(hr);
    unsigned ul = __float_as_uint(lf);
    *h = (ushort_t)(hr >> 16);
    *l = (ushort_t)((ul + 0x7fffu + ((ul >> 16) & 1u)) >> 16);
}

// async global->LDS, 16B per lane; LDS dest = wave-uniform base + lane*16 (HW requirement)
__device__ __forceinline__ void gload16(const void* g, void* l) {
    __builtin_amdgcn_global_load_lds(
        (const __attribute__((address_space(1))) unsigned int*)g,
        (__attribute__((address_space(3))) unsigned int*)l, 16, 0, 0);
}

// ===== activation layout: row record = 256 ushorts: [0:128]=hi[k], [128:256]=lo[k] =====

__global__ __launch_bounds__(256) void split_rows_k(
    const float* __restrict__ src, ushort_t* __restrict__ dst, int total)
{
    for (int i = blockIdx.x * 256 + threadIdx.x; i < total; i += gridDim.x * 256) {
        int row = i >> 7, c = i & 127;
        ushort_t h, l;
        split1(src[i], &h, &l);
        dst[(size_t)row * 256 + c] = h;
        dst[(size_t)row * 256 + 128 + c] = l;
    }
}

__global__ __launch_bounds__(256) void convert_out_k(
    const ushort_t* __restrict__ src, float* __restrict__ dst, int total)
{
    for (int i = blockIdx.x * 256 + threadIdx.x; i < total; i += gridDim.x * 256) {
        int row = i >> 7, c = i & 127;
        dst[i] = recf(src[(size_t)row * 256 + c], src[(size_t)row * 256 + 128 + c]);
    }
}

// ======== weight prep: fragment-major packed layouts ========
// frag id: (((kt*NT + tile)*64 + lane)*8 + j); elem = W^T[n = tile*16 + (lane&15)][k = kt*32 + (lane>>4)*8 + j]

__global__ __launch_bounds__(256) void pack_mlp_frag(
    const float* __restrict__ W, ushort_t* __restrict__ Wh, ushort_t* __restrict__ Wl)
{
    int fid = blockIdx.x * 256 + threadIdx.x;   // 3*4*8*64 = 6144
    if (fid >= 6144) return;
    int lane = fid & 63;
    int tile = (fid >> 6) & 7;
    int kt = (fid >> 9) & 3;
    int layer = fid >> 11;
    int l15 = lane & 15, lg = lane >> 4;
    int n = tile * 16 + l15;
#pragma unroll
    for (int j = 0; j < 8; j++) {
        int k = kt * 32 + lg * 8 + j;
        ushort_t h, l;
        splitw(W[layer * 16384 + k * 128 + n], &h, &l);
        Wh[(size_t)fid * 8 + j] = h;
        Wl[(size_t)fid * 8 + j] = l;
    }
}

__global__ __launch_bounds__(256) void pack_lstm_frag(
    const float* __restrict__ Wih, const float* __restrict__ Whh, int kih, int nstep,
    ushort_t* __restrict__ Wh, ushort_t* __restrict__ Wl)
{
    int fid = blockIdx.x * 256 + threadIdx.x;   // nstep*32*64
    if (fid >= nstep * 2048) return;
    int lane = fid & 63;
    int tile = (fid >> 6) & 31;
    int kt = fid >> 11;
    int l15 = lane & 15, lg = lane >> 4;
    int n = tile * 16 + l15;
#pragma unroll
    for (int j = 0; j < 8; j++) {
        int k = kt * 32 + lg * 8 + j;
        float v = (k < kih) ? Wih[n * kih + k] : Whh[(n << 7) + (k - kih)];
        ushort_t h, l;
        splitw(v, &h, &l);
        Wh[(size_t)fid * 8 + j] = h;
        Wl[(size_t)fid * 8 + j] = l;
    }
}

// ================= CSR build (once per call) =================
__global__ __launch_bounds__(256) void csr_hist_k(
    const int* __restrict__ ps, const int* __restrict__ pd,
    const int* __restrict__ ns, const int* __restrict__ nd,
    int* __restrict__ cnt_c, int* __restrict__ cnt_l)
{
    int e = blockIdx.x * 256 + threadIdx.x;
    if (e >= NE) return;
    atomicAdd(&cnt_c[pd[e]], 1);
    atomicAdd(&cnt_c[nd[e]], 1);
    atomicAdd(&cnt_l[ps[e]], 1);
    atomicAdd(&cnt_l[NV + ns[e]], 1);
}

__global__ __launch_bounds__(256) void scan_p1(
    const int* __restrict__ cnt, int* __restrict__ partials, int n)
{
    __shared__ int sdata[256];
    int t = threadIdx.x, b = blockIdx.x;
    int base = b * 1024 + t * 4;
    int s = 0;
#pragma unroll
    for (int j = 0; j < 4; j++) { int i = base + j; if (i < n) s += cnt[i]; }
    sdata[t] = s; __syncthreads();
    for (int st = 128; st > 0; st >>= 1) {
        if (t < st) sdata[t] += sdata[t + st];
        __syncthreads();
    }
    if (t == 0) partials[b] = sdata[0];
}

__global__ __launch_bounds__(256) void scan_p2(int* __restrict__ partials, int nb, int* __restrict__ rowptr_end)
{
    __shared__ int sdata[256];
    int t = threadIdx.x;
    int v = (t < nb) ? partials[t] : 0;
    int x = v;
    sdata[t] = x; __syncthreads();
    for (int st = 1; st < 256; st <<= 1) {
        int y = (t >= st) ? sdata[t - st] : 0;
        __syncthreads();
        x += y; sdata[t] = x;
        __syncthreads();
    }
    if (t < nb) partials[t] = x - v;
    if (t == 255) *rowptr_end = sdata[255];
}

__global__ __launch_bounds__(256) void scan_p3(
    const int* __restrict__ cnt, const int* __restrict__ partials,
    int* __restrict__ rowptr, int* __restrict__ cursor, int n)
{
    __shared__ int sdata[256];
    int t = threadIdx.x, b = blockIdx.x;
    int base = b * 1024 + t * 4;
    int v[4]; int s = 0;
#pragma unroll
    for (int j = 0; j < 4; j++) { int i = base + j; v[j] = (i < n) ? cnt[i] : 0; s += v[j]; }
    int x = s;
    sdata[t] = x; __syncthreads();
    for (int st = 1; st < 256; st <<= 1) {
        int y = (t >= st) ? sdata[t - st] : 0;
        __syncthreads();
        x += y; sdata[t] = x;
        __syncthreads();
    }
    int off = partials[b] + x - s;
#pragma unroll
    for (int j = 0; j < 4; j++) {
        int i = base + j;
        if (i < n) { rowptr[i] = off; cursor[i] = off; off += v[j]; }
    }
}

__global__ __launch_bounds__(256) void csr_fill_k(
    const int* __restrict__ ps, const int* __restrict__ pd,
    const int* __restrict__ ns, const int* __restrict__ nd,
    int* __restrict__ cur_c, int* __restrict__ eidx_c,
    int* __restrict__ cur_l, int* __restrict__ eidx_l)
{
    int e = blockIdx.x * 256 + threadIdx.x;
    if (e >= NE) return;
    int p;
    p = atomicAdd(&cur_c[pd[e]], 1); eidx_c[p] = ps[e];
    p = atomicAdd(&cur_c[nd[e]], 1); eidx_c[p] = NV + ns[e];
    p = atomicAdd(&cur_l[ps[e]], 1); eidx_l[p] = pd[e];
    p = atomicAdd(&cur_l[NV + ns[e]], 1); eidx_l[p] = nd[e];
}

// ---- gather-sum over split rows: out[row] = sum msg[eidx[j]] ; one wave per row ----
__global__ __launch_bounds__(256) void gather_sum_k(
    const ushort_t* __restrict__ msg, const int* __restrict__ rowptr,
    const int* __restrict__ eidx, ushort_t* __restrict__ out, int nrows)
{
    int row = (blockIdx.x * 256 + threadIdx.x) >> 6;
    if (row >= nrows) return;
    int lane = threadIdx.x & 63;
    int beg = rowptr[row], end = rowptr[row + 1];
    float a0 = 0.f, a1 = 0.f;
    for (int j = beg; j < end; j++) {
        int src = eidx[j];
        const ushort_t* p = msg + (size_t)src * 256 + lane * 2;
        unsigned hp = *reinterpret_cast<const unsigned*>(p);
        unsigned lp = *reinterpret_cast<const unsigned*>(p + 128);
        a0 += __uint_as_float(hp << 16) + __uint_as_float(lp << 16);
        a1 += __uint_as_float(hp & 0xffff0000u) + __uint_as_float(lp & 0xffff0000u);
    }
    ushort_t h0, l0, h1, l1;
    split1(a0, &h0, &l0);
    split1(a1, &h1, &l1);
    ushort_t* op = out + (size_t)row * 256 + lane * 2;
    *reinterpret_cast<unsigned*>(op) = (unsigned)h0 | ((unsigned)h1 << 16);
    *reinterpret_cast<unsigned*>(op + 128) = (unsigned)l0 | ((unsigned)l1 << 16);
}

// ---------------- fused 3-layer MLP: split-plane input/output, LDS activation bounce ----------------
__global__ __launch_bounds__(256, 4) void mlp3_v5(
    const ushort_t* __restrict__ x, const ushort_t* __restrict__ Wh,
    const ushort_t* __restrict__ Wl, const float* __restrict__ bias,
    ushort_t* __restrict__ y, int M)
{
    __shared__ ushort_t Xh[64][136];
    __shared__ ushort_t Xl[64][136];
    const int t = threadIdx.x;
    const int rb = blockIdx.x * 64;
    const int lane = t & 63, w = t >> 6, wr = w >> 1, wc = w & 1;
    const int l15 = lane & 15, lg = lane >> 4;

#pragma unroll
    for (int j = 0; j < 8; j++) {
        int idx = t + 256 * j;             // [0,2048)
        int plane = idx >> 10, rem = idx & 1023;
        int r = rem >> 4, c8 = (rem & 15) * 8;
        int gr = rb + r; if (gr >= M) gr = M - 1;
        uint4 v = *reinterpret_cast<const uint4*>(x + (size_t)gr * 256 + plane * 128 + c8);
        ushort_t* dst = plane ? &Xl[r][c8] : &Xh[r][c8];
        *reinterpret_cast<uint4*>(dst) = v;
    }
    __syncthreads();

    for (int layer = 0; layer < 3; layer++) {
        f32x4 acc[2][4];
#pragma unroll
        for (int m = 0; m < 2; m++)
#pragma unroll
            for (int nf = 0; nf < 4; nf++) acc[m][nf] = f32x4{0.f, 0.f, 0.f, 0.f};

        short8 bh[4], bl[4], bhn[4], bln[4];
#pragma unroll
        for (int nf = 0; nf < 4; nf++) {
            int tile = wc * 4 + nf;
            size_t off = ((size_t)((layer * 4 + 0) * 8 + tile) * 64 + lane) * 8;
            bh[nf] = *reinterpret_cast<const short8*>(Wh + off);
            bl[nf] = *reinterpret_cast<const short8*>(Wl + off);
        }

#pragma unroll
        for (int kt = 0; kt < 4; kt++) {
            short8 ah[2], al[2];
#pragma unroll
            for (int m = 0; m < 2; m++) {
                int row = wr * 32 + m * 16 + l15;
                ah[m] = *reinterpret_cast<const short8*>(&Xh[row][kt * 32 + lg * 8]);
                al[m] = *reinterpret_cast<const short8*>(&Xl[row][kt * 32 + lg * 8]);
            }
            if (kt < 3) {
#pragma unroll
                for (int nf = 0; nf < 4; nf++) {
                    int tile = wc * 4 + nf;
                    size_t off = ((size_t)((layer * 4 + kt + 1) * 8 + tile) * 64 + lane) * 8;
                    bhn[nf] = *reinterpret_cast<const short8*>(Wh + off);
                    bln[nf] = *reinterpret_cast<const short8*>(Wl + off);
                }
            }
#pragma unroll
            for (int nf = 0; nf < 4; nf++)
#pragma unroll
                for (int m = 0; m < 2; m++)
                    acc[m][nf] = __builtin_amdgcn_mfma_f32_16x16x32_bf16(ah[m], bh[nf], acc[m][nf], 0, 0, 0);
#pragma unroll
            for (int nf = 0; nf < 4; nf++)
#pragma unroll
                for (int m = 0; m < 2; m++)
                    acc[m][nf] = __builtin_amdgcn_mfma_f32_16x16x32_bf16(ah[m], bl[nf], acc[m][nf], 0, 0, 0);
#pragma unroll
            for (int nf = 0; nf < 4; nf++)
#pragma unroll
                for (int m = 0; m < 2; m++)
                    acc[m][nf] = __builtin_amdgcn_mfma_f32_16x16x32_bf16(al[m], bh[nf], acc[m][nf], 0, 0, 0);
            if (kt < 3) {
#pragma unroll
                for (int nf = 0; nf < 4; nf++) { bh[nf] = bhn[nf]; bl[nf] = bln[nf]; }
            }
        }

        float bv[4];
#pragma unroll
        for (int nf = 0; nf < 4; nf++) bv[nf] = bias[layer * 128 + wc * 64 + nf * 16 + l15];
        __syncthreads();   // all Xh/Xl reads done
        if (layer < 2) {
#pragma unroll
            for (int m = 0; m < 2; m++)
#pragma unroll
                for (int nf = 0; nf < 4; nf++)
#pragma unroll
                    for (int rr = 0; rr < 4; rr++) {
                        float v = fmaxf(acc[m][nf][rr] + bv[nf], 0.f);
                        ushort_t h, l;
                        split1(v, &h, &l);
                        int rw = wr * 32 + m * 16 + lg * 4 + rr;
                        int cl = wc * 64 + nf * 16 + l15;
                        Xh[rw][cl] = h;
                        Xl[rw][cl] = l;
                    }
            __syncthreads();
        } else {
#pragma unroll
            for (int m = 0; m < 2; m++)
#pragma unroll
                for (int rr = 0; rr < 4; rr++) {
                    int gr = rb + wr * 32 + m * 16 + lg * 4 + rr;
                    if (gr < M) {
#pragma unroll
                        for (int nf = 0; nf < 4; nf++) {
                            float v = acc[m][nf][rr] + bv[nf];
                            ushort_t h, l;
                            split1(v, &h, &l);
                            size_t p = (size_t)gr * 256 + wc * 64 + nf * 16 + l15;
                            y[p] = h;
                            y[p + 128] = l;
                        }
                    }
                }
        }
    }
}

// ---------------- LSTM v10: global_load_lds double-buffer (unsinkable issue-early) ----------------
// Block 512 thr / 8 waves; tile = 64 rows x 256 gate-cols (slice s in {0,1}: cols s*64.. of EACH gate).
// Wave = 16 rows (wr=w>>1) x 128 cols (wc=w&1); acc[8] (g*2+u). One barrier per kt.
// LDS: B dbuf 2x32KB (32 slots x 1KB: slot = sel*16 + g*4 + wc*2+u), A dbuf 2x8KB (8 slots:
// plane*4 + row-tile). All staging via global_load_lds: per thread per kt = 4 B + 1 A issues,
// issued BEFORE the MFMA cluster -> latency hides under compute; barrier drains a ready prefetch.
// Grid: wg = r8 + 8*(2*q + s) so both slices of tile (r8,q) share one XCD's L2 (A fetched once).
template <int NKT, bool FLIP>
__global__ __launch_bounds__(512, 4) void lstm_v10(
    const ushort_t* __restrict__ A0, const ushort_t* __restrict__ A1, const ushort_t* __restrict__ A2,
    const ushort_t* __restrict__ Bh_g, const ushort_t* __restrict__ Bl_g,
    const float* __restrict__ bih, const float* __restrict__ bhh,
    float* __restrict__ c_st, ushort_t* __restrict__ h_out, int M)
{
    __shared__ ushort_t Bs[2][32 * 512];   // 2 x 32KB
    __shared__ ushort_t As[2][8 * 512];    // 2 x 8KB
    const int wg = blockIdx.x;
    const int r8 = wg & 7, j = wg >> 3;
    const int s = j & 1;
    const int tile_id = r8 + 8 * (j >> 1);
    const int rb = tile_id * 64;
    if (rb >= M) return;                   // padding block (uniform exit)

    const int t = threadIdx.x;
    const int lane = t & 63, w = t >> 6, wr = w >> 1, wc = w & 1;
    const int l15 = lane & 15, lg = lane >> 4;

    // ---- staging helpers (global_load_lds: LDS dest wave-uniform base + lane*16) ----
    auto stageB = [&](int kt, int buf) {
#pragma unroll
        for (int i = 0; i < 4; i++) {
            int slot = w + 8 * i;                  // wave-uniform
            int sel = slot >> 4, lt = slot & 15;
            int g = lt >> 2, v = lt & 3;
            int gt = g * 8 + s * 4 + v;
            const ushort_t* src = sel ? Bl_g : Bh_g;
            gload16(src + ((size_t)(kt * 32 + gt) * 64 + lane) * 8,
                    &Bs[buf][(size_t)slot * 512 + lane * 8]);
        }
    };
    auto stageA = [&](int kt, int buf) {
        int slot = w;                              // wave-uniform
        int p = slot >> 2, tl = slot & 3;
        const int seg = kt >> 2;
        const ushort_t* src = (seg == 0) ? A0 : ((seg == 1) ? A1 : A2);
        int row = rb + tl * 16 + (lane & 15);
        if (row >= M) row = M - 1;
        if (FLIP && seg == 1) row = (row < NV) ? row + NV : row - NV;
        gload16(src + (size_t)row * 256 + p * 128 + (kt & 3) * 32 + (lane >> 4) * 8,
                &As[buf][(size_t)slot * 512 + lane * 8]);
    };

    f32x4 acc[8];
#pragma unroll
    for (int i = 0; i < 8; i++) acc[i] = f32x4{0.f, 0.f, 0.f, 0.f};

    // prologue: stage kt=0 into buffer 0
    stageB(0, 0);
    stageA(0, 0);
    __syncthreads();

    int cur = 0;
#pragma unroll
    for (int kt = 0; kt < NKT; kt++) {
        // (1) issue next kt's stages FIRST (unsinkable; drain under this kt's compute)
        if (kt + 1 < NKT) {
            stageB(kt + 1, cur ^ 1);
            stageA(kt + 1, cur ^ 1);
        }
        // (2) compute current kt from LDS
        const ushort_t* Ab = As[cur];
        const ushort_t* Bb = Bs[cur];
        short8 ah = *reinterpret_cast<const short8*>(&Ab[(size_t)(0 + wr) * 512 + lane * 8]);
        short8 al = *reinterpret_cast<const short8*>(&Ab[(size_t)(4 + wr) * 512 + lane * 8]);
#pragma unroll
        for (int g = 0; g < 4; g++)
#pragma unroll
            for (int u = 0; u < 2; u++) {
                int lt = g * 4 + wc * 2 + u;
                short8 bh = *reinterpret_cast<const short8*>(&Bb[(size_t)lt * 512 + lane * 8]);
                short8 bl = *reinterpret_cast<const short8*>(&Bb[(size_t)(16 + lt) * 512 + lane * 8]);
                int idx = g * 2 + u;
                acc[idx] = __builtin_amdgcn_mfma_f32_16x16x32_bf16(ah, bh, acc[idx], 0, 0, 0);
                acc[idx] = __builtin_amdgcn_mfma_f32_16x16x32_bf16(ah, bl, acc[idx], 0, 0, 0);
                acc[idx] = __builtin_amdgcn_mfma_f32_16x16x32_bf16(al, bh, acc[idx], 0, 0, 0);
            }
        // (3) single barrier: drains prefetch (vmcnt) + guards buffer reuse
        __syncthreads();
        cur ^= 1;
    }

    // epilogue: bias + activations + state update; h written in split format
    float bs4[4][2];
#pragma unroll
    for (int g = 0; g < 4; g++)
#pragma unroll
        for (int u = 0; u < 2; u++) {
            int colc = s * 64 + wc * 32 + u * 16 + l15;
            bs4[g][u] = bih[g * 128 + colc] + bhh[g * 128 + colc];
        }
#pragma unroll
    for (int rr = 0; rr < 4; rr++) {
        int gr = rb + wr * 16 + lg * 4 + rr;
        if (gr >= M) continue;
#pragma unroll
        for (int u = 0; u < 2; u++) {
            int colc = s * 64 + wc * 32 + u * 16 + l15;
            float gi = acc[0 + u][rr] + bs4[0][u];
            float gf = acc[2 + u][rr] + bs4[1][u];
            float gg = acc[4 + u][rr] + bs4[2][u];
            float go = acc[6 + u][rr] + bs4[3][u];
            size_t pc = (size_t)gr * 128 + colc;
            float cold = c_st[pc];
            float cn = sigf(gf) * cold + sigf(gi) * tanhf(gg);
            float hn = sigf(go) * tanhf(cn);
            c_st[pc] = cn;
            ushort_t hh, hl;
            split1(hn, &hh, &hl);
            size_t ph = (size_t)gr * 256 + colc;
            h_out[ph] = hh;
            h_out[ph + 128] = hl;
        }
    }
}

extern "C" void kernel_launch(void* const* d_in, const int* in_sizes, int n_in,
                              void* d_out, int out_size, void* d_ws, size_t ws_size,
                              hipStream_t stream)
{
    const float* l_pos   = (const float*)d_in[0];
    const float* l_neg   = (const float*)d_in[1];
    const float* c_emb   = (const float*)d_in[2];
    const float* l_mlp_W = (const float*)d_in[3];
    const float* l_mlp_b = (const float*)d_in[4];
    const float* c_mlp_W = (const float*)d_in[5];
    const float* c_mlp_b = (const float*)d_in[6];
    const float* l_Wih   = (const float*)d_in[7];
    const float* l_Whh   = (const float*)d_in[8];
    const float* l_bih   = (const float*)d_in[9];
    const float* l_bhh   = (const float*)d_in[10];
    const float* c_Wih   = (const float*)d_in[11];
    const float* c_Whh   = (const float*)d_in[12];
    const float* c_bih   = (const float*)d_in[13];
    const float* c_bhh   = (const float*)d_in[14];
    const int* pos_src   = (const int*)d_in[15];
    const int* pos_dst   = (const int*)d_in[16];
    const int* neg_src   = (const int*)d_in[17];
    const int* neg_dst   = (const int*)d_in[18];

    float* out = (float*)d_out;
    // d_out doubles as the h-state PONG buffers during rounds (dead by final convert):
    ushort_t* l_hQ = (ushort_t*)d_out;                       // NL rows x 512B
    ushort_t* c_hQ = (ushort_t*)(out + (size_t)NL * 128);    // NC rows x 512B

    float* wsp = (float*)d_ws;
    ushort_t* l_hP  = (ushort_t*)wsp; wsp += (size_t)NL * 128;   // literal h ping
    float*    l_c   = wsp;            wsp += (size_t)NL * 128;   // literal cell (f32)
    float*    c_c   = wsp;            wsp += (size_t)NC * 128;   // clause cell (f32)
    ushort_t* l_msg = (ushort_t*)wsp; wsp += (size_t)NL * 128;   // literal msg / c2l alias
    ushort_t* c_hP  = (ushort_t*)wsp; wsp += (size_t)NC * 128;   // clause h ping
    ushort_t* l2c   = (ushort_t*)wsp; wsp += (size_t)NC * 128;
    ushort_t* c2l = l_msg;  // gather #2 writes here after gather #1 consumed l_msg

    ushort_t* us = (ushort_t*)wsp;
    ushort_t* mlpLh = us; us += 3 * 128 * 128;
    ushort_t* mlpLl = us; us += 3 * 128 * 128;
    ushort_t* mlpCh = us; us += 3 * 128 * 128;
    ushort_t* mlpCl = us; us += 3 * 128 * 128;
    ushort_t* lstmLh = us; us += 512 * 384;
    ushort_t* lstmLl = us; us += 512 * 384;
    ushort_t* lstmCh = us; us += 512 * 256;
    ushort_t* lstmCl = us; us += 512 * 256;

    int* ip = (int*)us;
    int* cnt_c    = ip; ip += NC;
    int* rowptr_c = ip; ip += NC + 1;
    int* cur_c    = ip; ip += NC;
    int* eidx_c   = ip; ip += 2 * NE;
    int* cnt_l    = ip; ip += NL;
    int* rowptr_l = ip; ip += NL + 1;
    int* cur_l    = ip; ip += NL;
    int* eidx_l   = ip; ip += 2 * NE;
    int* part_c   = ip; ip += 256;
    int* part_l   = ip; ip += 256;

    // init states: split embeddings into ping buffers; zero cells
    split_rows_k<<<2048, 256, 0, stream>>>(l_pos, l_hP, NV * 128);
    split_rows_k<<<2048, 256, 0, stream>>>(l_neg, l_hP + (size_t)NV * 256, NV * 128);
    split_rows_k<<<2048, 256, 0, stream>>>(c_emb, c_hP, NC * 128);
    hipMemsetAsync(l_c, 0, (size_t)NL * 128 * 4, stream);
    hipMemsetAsync(c_c, 0, (size_t)NC * 128 * 4, stream);

    // pack weights (once per call)
    pack_mlp_frag<<<24, 256, 0, stream>>>(l_mlp_W, mlpLh, mlpLl);
    pack_mlp_frag<<<24, 256, 0, stream>>>(c_mlp_W, mlpCh, mlpCl);
    pack_lstm_frag<<<96, 256, 0, stream>>>(l_Wih, l_Whh, 256, 12, lstmLh, lstmLl);
    pack_lstm_frag<<<64, 256, 0, stream>>>(c_Wih, c_Whh, 128, 8, lstmCh, lstmCl);

    // ---- CSR build (once per call; graph static across rounds) ----
    hipMemsetAsync(cnt_c, 0, NC * sizeof(int), stream);
    hipMemsetAsync(cnt_l, 0, NL * sizeof(int), stream);
    constexpr int EB = (NE + 255) / 256;
    csr_hist_k<<<EB, 256, 0, stream>>>(pos_src, pos_dst, neg_src, neg_dst, cnt_c, cnt_l);
    constexpr int NBC = (NC + 1023) / 1024;
    constexpr int NBL = (NL + 1023) / 1024;
    scan_p1<<<NBC, 256, 0, stream>>>(cnt_c, part_c, NC);
    scan_p2<<<1, 256, 0, stream>>>(part_c, NBC, rowptr_c + NC);
    scan_p3<<<NBC, 256, 0, stream>>>(cnt_c, part_c, rowptr_c, cur_c, NC);
    scan_p1<<<NBL, 256, 0, stream>>>(cnt_l, part_l, NL);
    scan_p2<<<1, 256, 0, stream>>>(part_l, NBL, rowptr_l + NL);
    scan_p3<<<NBL, 256, 0, stream>>>(cnt_l, part_l, rowptr_l, cur_l, NL);
    csr_fill_k<<<EB, 256, 0, stream>>>(pos_src, pos_dst, neg_src, neg_dst,
                                       cur_c, eidx_c, cur_l, eidx_l);

    // LSTM grids: BM=64 tiles padded to x8; 2 slices; wg = r8 + 8*(2*q + s) keeps both
    // slices of a tile on one XCD (xcd = wg % 8 = r8)
    constexpr int TL64 = (NL + 63) / 64, TLP64 = ((TL64 + 7) / 8) * 8;   // 1563 -> 1568
    constexpr int TC64 = (NC + 63) / 64, TCP64 = ((TC64 + 7) / 8) * 8;   // 3125 -> 3128

    ushort_t* l_cur = l_hP;
    ushort_t* l_nxt = l_hQ;
    ushort_t* c_cur = c_hP;
    ushort_t* c_oth = c_hQ;

    for (int r = 0; r < NROUNDS; r++) {
        // MLPs: l_cur -> l_msg ; c_cur -> c_oth (c_msg lives in the dead clause-h buffer)
        mlp3_v5<<<(NL + 63) / 64, 256, 0, stream>>>(l_cur, mlpLh, mlpLl, l_mlp_b, l_msg, NL);
        mlp3_v5<<<(NC + 63) / 64, 256, 0, stream>>>(c_cur, mlpCh, mlpCl, c_mlp_b, c_oth, NC);

        // gathers: l2c from l_msg ; c2l (aliases l_msg) from c_oth
        gather_sum_k<<<NC * 64 / 256, 256, 0, stream>>>(l_msg, rowptr_c, eidx_c, l2c, NC);
        gather_sum_k<<<NL * 64 / 256, 256, 0, stream>>>(c_oth, rowptr_l, eidx_l, c2l, NL);

        // literal LSTM: x = [c2l | flip(l_cur) | l_cur] -> l_nxt (l_c in place)
        lstm_v10<12, true><<<2 * TLP64, 512, 0, stream>>>(
            c2l, l_cur, l_cur, lstmLh, lstmLl, l_bih, l_bhh, l_c, l_nxt, NL);
        // clause LSTM: x = [l2c | c_cur] -> h into c_oth (c_msg already consumed; c_c in place)
        lstm_v10<8, false><<<2 * TCP64, 512, 0, stream>>>(
            l2c, c_cur, nullptr, lstmCh, lstmCl, c_bih, c_bhh, c_c, c_oth, NC);

        ushort_t* t2 = l_cur; l_cur = l_nxt; l_nxt = t2;
        t2 = c_cur; c_cur = c_oth; c_oth = t2;
    }
    // 26 even rounds: l_cur == l_hP (ws), c_cur == c_hP (ws). Pongs in d_out are dead.
    convert_out_k<<<2048, 256, 0, stream>>>(l_hP, out, NL * 128);
    convert_out_k<<<2048, 256, 0, stream>>>(c_hP, out + (size_t)NL * 128, NC * 128);
    (void)in_sizes; (void)n_in; (void)out_size; (void)ws_size;
}

// Round 17
// 20303.961 us; speedup vs baseline: 1.2648x; 1.0082x over previous
//
#include <hip/hip_runtime.h>
#include <math.h>

typedef __attribute__((ext_vector_type(8))) short short8;
typedef __attribute__((ext_vector_type(4))) float f32x4;
typedef unsigned short ushort_t;

constexpr int NV = 50000;    // V
constexpr int NL = 100000;   // 2V literal rows
constexpr int NC = 200000;   // clauses
constexpr int NE = 300000;   // edges per polarity
constexpr int NROUNDS = 26;

// counted waitcnt (T4): literal immediate required
#define VMCNT(n) asm volatile("s_waitcnt vmcnt(" #n ")" ::: "memory")

// NOTE (r8 post-mortem): epilogue math must be relative-error-only. tanh via
// 1 - 2/(e^2x+1) has additive ~ulp(1)=6e-8 cancellation at small x -> breaks
// the 8.8e-8 threshold over 26 recurrent rounds. Keep libm tanhf.
__device__ __forceinline__ float sigf(float x) { return 1.0f / (1.0f + __expf(-x)); }

// f32 -> bf16 hi/lo split (truncation; h+l rel err ~2^-17)
__device__ __forceinline__ void split1(float x, ushort_t* h, ushort_t* l) {
    unsigned u = __float_as_uint(x);
    *h = (ushort_t)(u >> 16);
    float lf = x - __uint_as_float(u & 0xffff0000u);
    *l = (ushort_t)(__float_as_uint(lf) >> 16);
}
__device__ __forceinline__ float recf(ushort_t h, ushort_t l) {
    return __uint_as_float((unsigned)h << 16) + __uint_as_float((unsigned)l << 16);
}

// weight split with RTN on both halves (one-time prep)
__device__ __forceinline__ void splitw(float x, ushort_t* h, ushort_t* l) {
    unsigned u = __float_as_uint(x);
    unsigned hr = (u + 0x7fffu + ((u >> 16) & 1u)) & 0xffff0000u;
    float lf = x - __uint_as_float(hr);
    unsigned ul = __float_as_uint(lf);
    *h = (ushort_t)(hr >> 16);
    *l = (ushort_t)((ul + 0x7fffu + ((ul >> 16) & 1u)) >> 16);
}

// async global->LDS, 16B per lane; LDS dest = wave-uniform base + lane*16 (HW requirement)
__device__ __forceinline__ void gload16(const void* g, void* l) {
    __builtin_amdgcn_global_load_lds(
        (const __attribute__((address_space(1))) unsigned int*)g,
        (__attribute__((address_space(3))) unsigned int*)l, 16, 0, 0);
}

// ===== activation layout: row record = 256 ushorts: [0:128]=hi[k], [128:256]=lo[k] =====

__global__ __launch_bounds__(256) void split_rows_k(
    const float* __restrict__ src, ushort_t* __restrict__ dst, int total)
{
    for (int i = blockIdx.x * 256 + threadIdx.x; i < total; i += gridDim.x * 256) {
        int row = i >> 7, c = i & 127;
        ushort_t h, l;
        split1(src[i], &h, &l);
        dst[(size_t)row * 256 + c] = h;
        dst[(size_t)row * 256 + 128 + c] = l;
    }
}

__global__ __launch_bounds__(256) void convert_out_k(
    const ushort_t* __restrict__ src, float* __restrict__ dst, int total)
{
    for (int i = blockIdx.x * 256 + threadIdx.x; i < total; i += gridDim.x * 256) {
        int row = i >> 7, c = i & 127;
        dst[i] = recf(src[(size_t)row * 256 + c], src[(size_t)row * 256 + 128 + c]);
    }
}

// ======== weight prep: fragment-major packed layouts ========
// frag id: (((kt*NT + tile)*64 + lane)*8 + j); elem = W^T[n = tile*16 + (lane&15)][k = kt*32 + (lane>>4)*8 + j]

__global__ __launch_bounds__(256) void pack_mlp_frag(
    const float* __restrict__ W, ushort_t* __restrict__ Wh, ushort_t* __restrict__ Wl)
{
    int fid = blockIdx.x * 256 + threadIdx.x;   // 3*4*8*64 = 6144
    if (fid >= 6144) return;
    int lane = fid & 63;
    int tile = (fid >> 6) & 7;
    int kt = (fid >> 9) & 3;
    int layer = fid >> 11;
    int l15 = lane & 15, lg = lane >> 4;
    int n = tile * 16 + l15;
#pragma unroll
    for (int j = 0; j < 8; j++) {
        int k = kt * 32 + lg * 8 + j;
        ushort_t h, l;
        splitw(W[layer * 16384 + k * 128 + n], &h, &l);
        Wh[(size_t)fid * 8 + j] = h;
        Wl[(size_t)fid * 8 + j] = l;
    }
}

__global__ __launch_bounds__(256) void pack_lstm_frag(
    const float* __restrict__ Wih, const float* __restrict__ Whh, int kih, int nstep,
    ushort_t* __restrict__ Wh, ushort_t* __restrict__ Wl)
{
    int fid = blockIdx.x * 256 + threadIdx.x;   // nstep*32*64
    if (fid >= nstep * 2048) return;
    int lane = fid & 63;
    int tile = (fid >> 6) & 31;
    int kt = fid >> 11;
    int l15 = lane & 15, lg = lane >> 4;
    int n = tile * 16 + l15;
#pragma unroll
    for (int j = 0; j < 8; j++) {
        int k = kt * 32 + lg * 8 + j;
        float v = (k < kih) ? Wih[n * kih + k] : Whh[(n << 7) + (k - kih)];
        ushort_t h, l;
        splitw(v, &h, &l);
        Wh[(size_t)fid * 8 + j] = h;
        Wl[(size_t)fid * 8 + j] = l;
    }
}

// ================= CSR build (once per call) =================
__global__ __launch_bounds__(256) void csr_hist_k(
    const int* __restrict__ ps, const int* __restrict__ pd,
    const int* __restrict__ ns, const int* __restrict__ nd,
    int* __restrict__ cnt_c, int* __restrict__ cnt_l)
{
    int e = blockIdx.x * 256 + threadIdx.x;
    if (e >= NE) return;
    atomicAdd(&cnt_c[pd[e]], 1);
    atomicAdd(&cnt_c[nd[e]], 1);
    atomicAdd(&cnt_l[ps[e]], 1);
    atomicAdd(&cnt_l[NV + ns[e]], 1);
}

__global__ __launch_bounds__(256) void scan_p1(
    const int* __restrict__ cnt, int* __restrict__ partials, int n)
{
    __shared__ int sdata[256];
    int t = threadIdx.x, b = blockIdx.x;
    int base = b * 1024 + t * 4;
    int s = 0;
#pragma unroll
    for (int j = 0; j < 4; j++) { int i = base + j; if (i < n) s += cnt[i]; }
    sdata[t] = s; __syncthreads();
    for (int st = 128; st > 0; st >>= 1) {
        if (t < st) sdata[t] += sdata[t + st];
        __syncthreads();
    }
    if (t == 0) partials[b] = sdata[0];
}

__global__ __launch_bounds__(256) void scan_p2(int* __restrict__ partials, int nb, int* __restrict__ rowptr_end)
{
    __shared__ int sdata[256];
    int t = threadIdx.x;
    int v = (t < nb) ? partials[t] : 0;
    int x = v;
    sdata[t] = x; __syncthreads();
    for (int st = 1; st < 256; st <<= 1) {
        int y = (t >= st) ? sdata[t - st] : 0;
        __syncthreads();
        x += y; sdata[t] = x;
        __syncthreads();
    }
    if (t < nb) partials[t] = x - v;
    if (t == 255) *rowptr_end = sdata[255];
}

__global__ __launch_bounds__(256) void scan_p3(
    const int* __restrict__ cnt, const int* __restrict__ partials,
    int* __restrict__ rowptr, int* __restrict__ cursor, int n)
{
    __shared__ int sdata[256];
    int t = threadIdx.x, b = blockIdx.x;
    int base = b * 1024 + t * 4;
    int v[4]; int s = 0;
#pragma unroll
    for (int j = 0; j < 4; j++) { int i = base + j; v[j] = (i < n) ? cnt[i] : 0; s += v[j]; }
    int x = s;
    sdata[t] = x; __syncthreads();
    for (int st = 1; st < 256; st <<= 1) {
        int y = (t >= st) ? sdata[t - st] : 0;
        __syncthreads();
        x += y; sdata[t] = x;
        __syncthreads();
    }
    int off = partials[b] + x - s;
#pragma unroll
    for (int j = 0; j < 4; j++) {
        int i = base + j;
        if (i < n) { rowptr[i] = off; cursor[i] = off; off += v[j]; }
    }
}

__global__ __launch_bounds__(256) void csr_fill_k(
    const int* __restrict__ ps, const int* __restrict__ pd,
    const int* __restrict__ ns, const int* __restrict__ nd,
    int* __restrict__ cur_c, int* __restrict__ eidx_c,
    int* __restrict__ cur_l, int* __restrict__ eidx_l)
{
    int e = blockIdx.x * 256 + threadIdx.x;
    if (e >= NE) return;
    int p;
    p = atomicAdd(&cur_c[pd[e]], 1); eidx_c[p] = ps[e];
    p = atomicAdd(&cur_c[nd[e]], 1); eidx_c[p] = NV + ns[e];
    p = atomicAdd(&cur_l[ps[e]], 1); eidx_l[p] = pd[e];
    p = atomicAdd(&cur_l[NV + ns[e]], 1); eidx_l[p] = nd[e];
}

// ---- gather-sum over split rows: out[row] = sum msg[eidx[j]] ; one wave per row ----
__global__ __launch_bounds__(256) void gather_sum_k(
    const ushort_t* __restrict__ msg, const int* __restrict__ rowptr,
    const int* __restrict__ eidx, ushort_t* __restrict__ out, int nrows)
{
    int row = (blockIdx.x * 256 + threadIdx.x) >> 6;
    if (row >= nrows) return;
    int lane = threadIdx.x & 63;
    int beg = rowptr[row], end = rowptr[row + 1];
    float a0 = 0.f, a1 = 0.f;
    for (int j = beg; j < end; j++) {
        int src = eidx[j];
        const ushort_t* p = msg + (size_t)src * 256 + lane * 2;
        unsigned hp = *reinterpret_cast<const unsigned*>(p);
        unsigned lp = *reinterpret_cast<const unsigned*>(p + 128);
        a0 += __uint_as_float(hp << 16) + __uint_as_float(lp << 16);
        a1 += __uint_as_float(hp & 0xffff0000u) + __uint_as_float(lp & 0xffff0000u);
    }
    ushort_t h0, l0, h1, l1;
    split1(a0, &h0, &l0);
    split1(a1, &h1, &l1);
    ushort_t* op = out + (size_t)row * 256 + lane * 2;
    *reinterpret_cast<unsigned*>(op) = (unsigned)h0 | ((unsigned)h1 << 16);
    *reinterpret_cast<unsigned*>(op + 128) = (unsigned)l0 | ((unsigned)l1 << 16);
}

// ---------------- fused 3-layer MLP: split-plane input/output, LDS activation bounce ----------------
__global__ __launch_bounds__(256, 4) void mlp3_v5(
    const ushort_t* __restrict__ x, const ushort_t* __restrict__ Wh,
    const ushort_t* __restrict__ Wl, const float* __restrict__ bias,
    ushort_t* __restrict__ y, int M)
{
    __shared__ ushort_t Xh[64][136];
    __shared__ ushort_t Xl[64][136];
    const int t = threadIdx.x;
    const int rb = blockIdx.x * 64;
    const int lane = t & 63, w = t >> 6, wr = w >> 1, wc = w & 1;
    const int l15 = lane & 15, lg = lane >> 4;

#pragma unroll
    for (int j = 0; j < 8; j++) {
        int idx = t + 256 * j;             // [0,2048)
        int plane = idx >> 10, rem = idx & 1023;
        int r = rem >> 4, c8 = (rem & 15) * 8;
        int gr = rb + r; if (gr >= M) gr = M - 1;
        uint4 v = *reinterpret_cast<const uint4*>(x + (size_t)gr * 256 + plane * 128 + c8);
        ushort_t* dst = plane ? &Xl[r][c8] : &Xh[r][c8];
        *reinterpret_cast<uint4*>(dst) = v;
    }
    __syncthreads();

    for (int layer = 0; layer < 3; layer++) {
        f32x4 acc[2][4];
#pragma unroll
        for (int m = 0; m < 2; m++)
#pragma unroll
            for (int nf = 0; nf < 4; nf++) acc[m][nf] = f32x4{0.f, 0.f, 0.f, 0.f};

        short8 bh[4], bl[4], bhn[4], bln[4];
#pragma unroll
        for (int nf = 0; nf < 4; nf++) {
            int tile = wc * 4 + nf;
            size_t off = ((size_t)((layer * 4 + 0) * 8 + tile) * 64 + lane) * 8;
            bh[nf] = *reinterpret_cast<const short8*>(Wh + off);
            bl[nf] = *reinterpret_cast<const short8*>(Wl + off);
        }

#pragma unroll
        for (int kt = 0; kt < 4; kt++) {
            short8 ah[2], al[2];
#pragma unroll
            for (int m = 0; m < 2; m++) {
                int row = wr * 32 + m * 16 + l15;
                ah[m] = *reinterpret_cast<const short8*>(&Xh[row][kt * 32 + lg * 8]);
                al[m] = *reinterpret_cast<const short8*>(&Xl[row][kt * 32 + lg * 8]);
            }
            if (kt < 3) {
#pragma unroll
                for (int nf = 0; nf < 4; nf++) {
                    int tile = wc * 4 + nf;
                    size_t off = ((size_t)((layer * 4 + kt + 1) * 8 + tile) * 64 + lane) * 8;
                    bhn[nf] = *reinterpret_cast<const short8*>(Wh + off);
                    bln[nf] = *reinterpret_cast<const short8*>(Wl + off);
                }
            }
#pragma unroll
            for (int nf = 0; nf < 4; nf++)
#pragma unroll
                for (int m = 0; m < 2; m++)
                    acc[m][nf] = __builtin_amdgcn_mfma_f32_16x16x32_bf16(ah[m], bh[nf], acc[m][nf], 0, 0, 0);
#pragma unroll
            for (int nf = 0; nf < 4; nf++)
#pragma unroll
                for (int m = 0; m < 2; m++)
                    acc[m][nf] = __builtin_amdgcn_mfma_f32_16x16x32_bf16(ah[m], bl[nf], acc[m][nf], 0, 0, 0);
#pragma unroll
            for (int nf = 0; nf < 4; nf++)
#pragma unroll
                for (int m = 0; m < 2; m++)
                    acc[m][nf] = __builtin_amdgcn_mfma_f32_16x16x32_bf16(al[m], bh[nf], acc[m][nf], 0, 0, 0);
            if (kt < 3) {
#pragma unroll
                for (int nf = 0; nf < 4; nf++) { bh[nf] = bhn[nf]; bl[nf] = bln[nf]; }
            }
        }

        float bv[4];
#pragma unroll
        for (int nf = 0; nf < 4; nf++) bv[nf] = bias[layer * 128 + wc * 64 + nf * 16 + l15];
        __syncthreads();   // all Xh/Xl reads done
        if (layer < 2) {
#pragma unroll
            for (int m = 0; m < 2; m++)
#pragma unroll
                for (int nf = 0; nf < 4; nf++)
#pragma unroll
                    for (int rr = 0; rr < 4; rr++) {
                        float v = fmaxf(acc[m][nf][rr] + bv[nf], 0.f);
                        ushort_t h, l;
                        split1(v, &h, &l);
                        int rw = wr * 32 + m * 16 + lg * 4 + rr;
                        int cl = wc * 64 + nf * 16 + l15;
                        Xh[rw][cl] = h;
                        Xl[rw][cl] = l;
                    }
            __syncthreads();
        } else {
#pragma unroll
            for (int m = 0; m < 2; m++)
#pragma unroll
                for (int rr = 0; rr < 4; rr++) {
                    int gr = rb + wr * 32 + m * 16 + lg * 4 + rr;
                    if (gr < M) {
#pragma unroll
                        for (int nf = 0; nf < 4; nf++) {
                            float v = acc[m][nf][rr] + bv[nf];
                            ushort_t h, l;
                            split1(v, &h, &l);
                            size_t p = (size_t)gr * 256 + wc * 64 + nf * 16 + l15;
                            y[p] = h;
                            y[p + 128] = l;
                        }
                    }
                }
        }
    }
}

// ---------------- LSTM v11: v10 structure + raw s_barrier + counted vmcnt (T3/T4) ----------------
// Identical tiling/LDS/grid to v10. Sync scheme per kt:
//   compute(cur) -> s_barrier (readers done) -> stage(kt+2 -> cur) -> vmcnt(5) (stage(kt+1)
//   landed; its loads were issued a FULL iteration ago) -> s_barrier -> flip.
// Steady-state outstanding = 10 per wave (2 stages x 5); wait to <=5 = exactly stage(kt+1).
// Never vmcnt(0) in the main loop (T4). Prologue primes 2 stages; tail steps down via vmcnt(0).
template <int NKT, bool FLIP>
__global__ __launch_bounds__(512, 4) void lstm_v11(
    const ushort_t* __restrict__ A0, const ushort_t* __restrict__ A1, const ushort_t* __restrict__ A2,
    const ushort_t* __restrict__ Bh_g, const ushort_t* __restrict__ Bl_g,
    const float* __restrict__ bih, const float* __restrict__ bhh,
    float* __restrict__ c_st, ushort_t* __restrict__ h_out, int M)
{
    __shared__ ushort_t Bs[2][32 * 512];   // 2 x 32KB
    __shared__ ushort_t As[2][8 * 512];    // 2 x 8KB
    const int wg = blockIdx.x;
    const int r8 = wg & 7, j = wg >> 3;
    const int s = j & 1;
    const int tile_id = r8 + 8 * (j >> 1);
    const int rb = tile_id * 64;
    if (rb >= M) return;                   // padding block (uniform exit)

    const int t = threadIdx.x;
    const int lane = t & 63, w = t >> 6, wr = w >> 1, wc = w & 1;
    const int l15 = lane & 15, lg = lane >> 4;

    // ---- staging helpers (global_load_lds: unsinkable, 5 vmcnt ops per wave per stage) ----
    auto stageB = [&](int kt, int buf) {
#pragma unroll
        for (int i = 0; i < 4; i++) {
            int slot = w + 8 * i;                  // wave-uniform
            int sel = slot >> 4, lt = slot & 15;
            int g = lt >> 2, v = lt & 3;
            int gt = g * 8 + s * 4 + v;
            const ushort_t* src = sel ? Bl_g : Bh_g;
            gload16(src + ((size_t)(kt * 32 + gt) * 64 + lane) * 8,
                    &Bs[buf][(size_t)slot * 512 + lane * 8]);
        }
    };
    auto stageA = [&](int kt, int buf) {
        int slot = w;                              // wave-uniform
        int p = slot >> 2, tl = slot & 3;
        const int seg = kt >> 2;
        const ushort_t* src = (seg == 0) ? A0 : ((seg == 1) ? A1 : A2);
        int row = rb + tl * 16 + (lane & 15);
        if (row >= M) row = M - 1;
        if (FLIP && seg == 1) row = (row < NV) ? row + NV : row - NV;
        gload16(src + (size_t)row * 256 + p * 128 + (kt & 3) * 32 + (lane >> 4) * 8,
                &As[buf][(size_t)slot * 512 + lane * 8]);
    };

    f32x4 acc[8];
#pragma unroll
    for (int i = 0; i < 8; i++) acc[i] = f32x4{0.f, 0.f, 0.f, 0.f};

    // prologue: prime both buffers (stage(0) drained; stage(1) left in flight)
    stageB(0, 0);
    stageA(0, 0);
    VMCNT(0);
    __builtin_amdgcn_s_barrier();
    stageB(1, 1);
    stageA(1, 1);

    int cur = 0;
#pragma unroll
    for (int kt = 0; kt < NKT; kt++) {
        // (1) compute current kt from LDS (stage(kt+1) loads drain underneath)
        const ushort_t* Ab = As[cur];
        const ushort_t* Bb = Bs[cur];
        short8 ah = *reinterpret_cast<const short8*>(&Ab[(size_t)(0 + wr) * 512 + lane * 8]);
        short8 al = *reinterpret_cast<const short8*>(&Ab[(size_t)(4 + wr) * 512 + lane * 8]);
#pragma unroll
        for (int g = 0; g < 4; g++)
#pragma unroll
            for (int u = 0; u < 2; u++) {
                int lt = g * 4 + wc * 2 + u;
                short8 bh = *reinterpret_cast<const short8*>(&Bb[(size_t)lt * 512 + lane * 8]);
                short8 bl = *reinterpret_cast<const short8*>(&Bb[(size_t)(16 + lt) * 512 + lane * 8]);
                int idx = g * 2 + u;
                acc[idx] = __builtin_amdgcn_mfma_f32_16x16x32_bf16(ah, bh, acc[idx], 0, 0, 0);
                acc[idx] = __builtin_amdgcn_mfma_f32_16x16x32_bf16(ah, bl, acc[idx], 0, 0, 0);
                acc[idx] = __builtin_amdgcn_mfma_f32_16x16x32_bf16(al, bh, acc[idx], 0, 0, 0);
            }

        if (kt + 1 < NKT) {
            // (2) all waves done READING cur (their ds_reads completed before their MFMAs issued)
            __builtin_amdgcn_s_barrier();
            // (3) refill cur with kt+2; wait ONLY for stage(kt+1) (issued one full iter ago)
            if (kt + 2 < NKT) {
                stageB(kt + 2, cur);
                stageA(kt + 2, cur);
                VMCNT(5);
            } else {
                VMCNT(0);   // tail: no stage(kt+2); drain the last prefetch
            }
            __builtin_amdgcn_sched_barrier(0);
            // (4) every wave's stage(kt+1) landed -> buffer nb readable by all
            __builtin_amdgcn_s_barrier();
        }
        cur ^= 1;
    }

    // epilogue: bias + activations + state update; h written in split format
    float bs4[4][2];
#pragma unroll
    for (int g = 0; g < 4; g++)
#pragma unroll
        for (int u = 0; u < 2; u++) {
            int colc = s * 64 + wc * 32 + u * 16 + l15;
            bs4[g][u] = bih[g * 128 + colc] + bhh[g * 128 + colc];
        }
#pragma unroll
    for (int rr = 0; rr < 4; rr++) {
        int gr = rb + wr * 16 + lg * 4 + rr;
        if (gr >= M) continue;
#pragma unroll
        for (int u = 0; u < 2; u++) {
            int colc = s * 64 + wc * 32 + u * 16 + l15;
            float gi = acc[0 + u][rr] + bs4[0][u];
            float gf = acc[2 + u][rr] + bs4[1][u];
            float gg = acc[4 + u][rr] + bs4[2][u];
            float go = acc[6 + u][rr] + bs4[3][u];
            size_t pc = (size_t)gr * 128 + colc;
            float cold = c_st[pc];
            float cn = sigf(gf) * cold + sigf(gi) * tanhf(gg);
            float hn = sigf(go) * tanhf(cn);
            c_st[pc] = cn;
            ushort_t hh, hl;
            split1(hn, &hh, &hl);
            size_t ph = (size_t)gr * 256 + colc;
            h_out[ph] = hh;
            h_out[ph + 128] = hl;
        }
    }
}

extern "C" void kernel_launch(void* const* d_in, const int* in_sizes, int n_in,
                              void* d_out, int out_size, void* d_ws, size_t ws_size,
                              hipStream_t stream)
{
    const float* l_pos   = (const float*)d_in[0];
    const float* l_neg   = (const float*)d_in[1];
    const float* c_emb   = (const float*)d_in[2];
    const float* l_mlp_W = (const float*)d_in[3];
    const float* l_mlp_b = (const float*)d_in[4];
    const float* c_mlp_W = (const float*)d_in[5];
    const float* c_mlp_b = (const float*)d_in[6];
    const float* l_Wih   = (const float*)d_in[7];
    const float* l_Whh   = (const float*)d_in[8];
    const float* l_bih   = (const float*)d_in[9];
    const float* l_bhh   = (const float*)d_in[10];
    const float* c_Wih   = (const float*)d_in[11];
    const float* c_Whh   = (const float*)d_in[12];
    const float* c_bih   = (const float*)d_in[13];
    const float* c_bhh   = (const float*)d_in[14];
    const int* pos_src   = (const int*)d_in[15];
    const int* pos_dst   = (const int*)d_in[16];
    const int* neg_src   = (const int*)d_in[17];
    const int* neg_dst   = (const int*)d_in[18];

    float* out = (float*)d_out;
    // d_out doubles as the h-state PONG buffers during rounds (dead by final convert):
    ushort_t* l_hQ = (ushort_t*)d_out;                       // NL rows x 512B
    ushort_t* c_hQ = (ushort_t*)(out + (size_t)NL * 128);    // NC rows x 512B

    float* wsp = (float*)d_ws;
    ushort_t* l_hP  = (ushort_t*)wsp; wsp += (size_t)NL * 128;   // literal h ping
    float*    l_c   = wsp;            wsp += (size_t)NL * 128;   // literal cell (f32)
    float*    c_c   = wsp;            wsp += (size_t)NC * 128;   // clause cell (f32)
    ushort_t* l_msg = (ushort_t*)wsp; wsp += (size_t)NL * 128;   // literal msg / c2l alias
    ushort_t* c_hP  = (ushort_t*)wsp; wsp += (size_t)NC * 128;   // clause h ping
    ushort_t* l2c   = (ushort_t*)wsp; wsp += (size_t)NC * 128;
    ushort_t* c2l = l_msg;  // gather #2 writes here after gather #1 consumed l_msg

    ushort_t* us = (ushort_t*)wsp;
    ushort_t* mlpLh = us; us += 3 * 128 * 128;
    ushort_t* mlpLl = us; us += 3 * 128 * 128;
    ushort_t* mlpCh = us; us += 3 * 128 * 128;
    ushort_t* mlpCl = us; us += 3 * 128 * 128;
    ushort_t* lstmLh = us; us += 512 * 384;
    ushort_t* lstmLl = us; us += 512 * 384;
    ushort_t* lstmCh = us; us += 512 * 256;
    ushort_t* lstmCl = us; us += 512 * 256;

    int* ip = (int*)us;
    int* cnt_c    = ip; ip += NC;
    int* rowptr_c = ip; ip += NC + 1;
    int* cur_c    = ip; ip += NC;
    int* eidx_c   = ip; ip += 2 * NE;
    int* cnt_l    = ip; ip += NL;
    int* rowptr_l = ip; ip += NL + 1;
    int* cur_l    = ip; ip += NL;
    int* eidx_l   = ip; ip += 2 * NE;
    int* part_c   = ip; ip += 256;
    int* part_l   = ip; ip += 256;

    // init states: split embeddings into ping buffers; zero cells
    split_rows_k<<<2048, 256, 0, stream>>>(l_pos, l_hP, NV * 128);
    split_rows_k<<<2048, 256, 0, stream>>>(l_neg, l_hP + (size_t)NV * 256, NV * 128);
    split_rows_k<<<2048, 256, 0, stream>>>(c_emb, c_hP, NC * 128);
    hipMemsetAsync(l_c, 0, (size_t)NL * 128 * 4, stream);
    hipMemsetAsync(c_c, 0, (size_t)NC * 128 * 4, stream);

    // pack weights (once per call)
    pack_mlp_frag<<<24, 256, 0, stream>>>(l_mlp_W, mlpLh, mlpLl);
    pack_mlp_frag<<<24, 256, 0, stream>>>(c_mlp_W, mlpCh, mlpCl);
    pack_lstm_frag<<<96, 256, 0, stream>>>(l_Wih, l_Whh, 256, 12, lstmLh, lstmLl);
    pack_lstm_frag<<<64, 256, 0, stream>>>(c_Wih, c_Whh, 128, 8, lstmCh, lstmCl);

    // ---- CSR build (once per call; graph static across rounds) ----
    hipMemsetAsync(cnt_c, 0, NC * sizeof(int), stream);
    hipMemsetAsync(cnt_l, 0, NL * sizeof(int), stream);
    constexpr int EB = (NE + 255) / 256;
    csr_hist_k<<<EB, 256, 0, stream>>>(pos_src, pos_dst, neg_src, neg_dst, cnt_c, cnt_l);
    constexpr int NBC = (NC + 1023) / 1024;
    constexpr int NBL = (NL + 1023) / 1024;
    scan_p1<<<NBC, 256, 0, stream>>>(cnt_c, part_c, NC);
    scan_p2<<<1, 256, 0, stream>>>(part_c, NBC, rowptr_c + NC);
    scan_p3<<<NBC, 256, 0, stream>>>(cnt_c, part_c, rowptr_c, cur_c, NC);
    scan_p1<<<NBL, 256, 0, stream>>>(cnt_l, part_l, NL);
    scan_p2<<<1, 256, 0, stream>>>(part_l, NBL, rowptr_l + NL);
    scan_p3<<<NBL, 256, 0, stream>>>(cnt_l, part_l, rowptr_l, cur_l, NL);
    csr_fill_k<<<EB, 256, 0, stream>>>(pos_src, pos_dst, neg_src, neg_dst,
                                       cur_c, eidx_c, cur_l, eidx_l);

    // LSTM grids: BM=64 tiles padded to x8; 2 slices; wg = r8 + 8*(2*q + s) keeps both
    // slices of a tile on one XCD (xcd = wg % 8 = r8)
    constexpr int TL64 = (NL + 63) / 64, TLP64 = ((TL64 + 7) / 8) * 8;   // 1563 -> 1568
    constexpr int TC64 = (NC + 63) / 64, TCP64 = ((TC64 + 7) / 8) * 8;   // 3125 -> 3128

    ushort_t* l_cur = l_hP;
    ushort_t* l_nxt = l_hQ;
    ushort_t* c_cur = c_hP;
    ushort_t* c_oth = c_hQ;

    for (int r = 0; r < NROUNDS; r++) {
        // MLPs: l_cur -> l_msg ; c_cur -> c_oth (c_msg lives in the dead clause-h buffer)
        mlp3_v5<<<(NL + 63) / 64, 256, 0, stream>>>(l_cur, mlpLh, mlpLl, l_mlp_b, l_msg, NL);
        mlp3_v5<<<(NC + 63) / 64, 256, 0, stream>>>(c_cur, mlpCh, mlpCl, c_mlp_b, c_oth, NC);

        // gathers: l2c from l_msg ; c2l (aliases l_msg) from c_oth
        gather_sum_k<<<NC * 64 / 256, 256, 0, stream>>>(l_msg, rowptr_c, eidx_c, l2c, NC);
        gather_sum_k<<<NL * 64 / 256, 256, 0, stream>>>(c_oth, rowptr_l, eidx_l, c2l, NL);

        // literal LSTM: x = [c2l | flip(l_cur) | l_cur] -> l_nxt (l_c in place)
        lstm_v11<12, true><<<2 * TLP64, 512, 0, stream>>>(
            c2l, l_cur, l_cur, lstmLh, lstmLl, l_bih, l_bhh, l_c, l_nxt, NL);
        // clause LSTM: x = [l2c | c_cur] -> h into c_oth (c_msg already consumed; c_c in place)
        lstm_v11<8, false><<<2 * TCP64, 512, 0, stream>>>(
            l2c, c_cur, nullptr, lstmCh, lstmCl, c_bih, c_bhh, c_c, c_oth, NC);

        ushort_t* t2 = l_cur; l_cur = l_nxt; l_nxt = t2;
        t2 = c_cur; c_cur = c_oth; c_oth = t2;
    }
    // 26 even rounds: l_cur == l_hP (ws), c_cur == c_hP (ws). Pongs in d_out are dead.
    convert_out_k<<<2048, 256, 0, stream>>>(l_hP, out, NL * 128);
    convert_out_k<<<2048, 256, 0, stream>>>(c_hP, out + (size_t)NL * 128, NC * 128);
    (void)in_sizes; (void)n_in; (void)out_size; (void)ws_size;
}